// Round 2
// baseline (1306.868 us; speedup 1.0000x reference)
//
#include <hip/hip_runtime.h>

// Integer-quantized MHA, exact integer semantics.
// B=2,H=16 -> BH=32 ; T=S=1024 ; HC=128 ; group G=8.
// out[t,c] = sum_s r[t,s] * (vt_q<<vt_s)[c,s]  -- OUTPUT WRITTEN AS INT32
// (harness reads d_out via np.int32 since reference returns an integer array)

typedef int v4i __attribute__((ext_vector_type(4)));

#define BH_N 32
#define T_N  1024
#define S_N  1024
#define HC_N 128
#define TT   16     // t rows per block
#define SB   64     // s cols per staged block
#define KST  132    // k_lds row stride (ints): 132 % 32 == 4 -> conflict-free b128 pattern
#define VST  68     // vt_lds row stride: 68 % 32 == 4
#define QST  132

__global__ __launch_bounds__(256)
void mha_int_kernel(const int* __restrict__ q_q, const int* __restrict__ q_s,
                    const int* __restrict__ k_q, const int* __restrict__ k_s,
                    const int* __restrict__ vt_q, const int* __restrict__ vt_s,
                    int* __restrict__ out)
{
    __shared__ int sc[TT][S_N];                                        // 64 KB: scores, then r
    __shared__ int kv[(SB*KST > HC_N*VST) ? SB*KST : HC_N*VST];        // 34 KB: k-block / vt-block
    __shared__ int qb[TT][QST];                                        // 8.4 KB: dequant q tile

    const int tid  = threadIdx.x;
    const int lane = tid & 63;
    const int wave = tid >> 6;
    const int bh   = blockIdx.y;
    const int t0   = blockIdx.x * TT;

    // ---- stage Q tile (dequantized: q_q << q_s), coalesced ----
    {
        const int ch = tid & 127;
        const int g  = ch >> 3;
        for (int r = tid >> 7; r < TT; r += 2) {
            int m   = q_q[(size_t)(bh * T_N + t0 + r) * HC_N + ch];
            int sft = q_s[(bh * T_N + t0 + r) * (HC_N / 8) + g];
            qb[r][ch] = m << sft;
        }
    }

    // ===================== QK: scores (exact int32) =====================
    // thread tile: rows {rq_, rq_+8}, cols {cq, cq+32}
    const int cq  = tid & 31;
    const int rq_ = tid >> 5;   // 0..7
    for (int sb = 0; sb < S_N / SB; ++sb) {
        __syncthreads();
        {   // stage k block rows [sb*SB, sb*SB+64), dequantized, layout kv[srow*KST + ch]
            const int ch = tid & 127;
            const int g  = ch >> 3;
            const int s0 = sb * SB;
            for (int sr = tid >> 7; sr < SB; sr += 2) {
                int m   = k_q[(size_t)(bh * S_N + s0 + sr) * HC_N + ch];
                int sft = k_s[(bh * S_N + s0 + sr) * (HC_N / 8) + g];
                kv[sr * KST + ch] = m << sft;
            }
        }
        __syncthreads();
        int a00 = 0, a01 = 0, a10 = 0, a11 = 0;
        const int* kp0 = &kv[cq * KST];
        const int* kp1 = &kv[(cq + 32) * KST];
        #pragma unroll 4
        for (int kk = 0; kk < HC_N; kk += 4) {
            v4i k0 = *(const v4i*)(kp0 + kk);
            v4i k1 = *(const v4i*)(kp1 + kk);
            v4i qa = *(const v4i*)(&qb[rq_][kk]);
            v4i qc = *(const v4i*)(&qb[rq_ + 8][kk]);
            #pragma unroll
            for (int j = 0; j < 4; ++j) {
                a00 += __mul24(qa[j], k0[j]);   // |q|<=1016, |k|<=1024: fits i24, exact
                a01 += __mul24(qa[j], k1[j]);
                a10 += __mul24(qc[j], k0[j]);
                a11 += __mul24(qc[j], k1[j]);
            }
        }
        sc[rq_][sb * SB + cq]          = a00;
        sc[rq_][sb * SB + cq + 32]     = a01;
        sc[rq_ + 8][sb * SB + cq]      = a10;
        sc[rq_ + 8][sb * SB + cq + 32] = a11;
    }
    __syncthreads();

    // ===================== softmax + per-group-of-8 quantization =====================
    // wave w owns rows 4w..4w+3; lane handles cols j*64+lane (group of 8 = 8 adjacent lanes)
    const float CSCALE = (float)(6.103515625e-05 / 11.313708498984760390566);  // 2^-14/sqrt(128), f32
    for (int rr = 0; rr < 4; ++rr) {
        const int row = wave * 4 + rr;
        float l[16];
        float mx = -3.0e38f;
        #pragma unroll
        for (int j = 0; j < 16; ++j) {
            l[j] = (float)sc[row][j * 64 + lane] * CSCALE;
            mx = fmaxf(mx, l[j]);
        }
        #pragma unroll
        for (int off = 32; off > 0; off >>= 1)
            mx = fmaxf(mx, __shfl_xor(mx, off, 64));
        float sum = 0.f;
        #pragma unroll
        for (int j = 0; j < 16; ++j) { l[j] = expf(l[j] - mx); sum += l[j]; }
        #pragma unroll
        for (int off = 32; off > 0; off >>= 1)
            sum += __shfl_xor(sum, off, 64);
        #pragma unroll
        for (int j = 0; j < 16; ++j) {
            float p   = l[j] / sum;                 // true division, matches reference
            float val = rintf(p * 16384.0f);        // round-half-even == jnp.round
            int iv = (int)val;
            int g  = iv;
            g = max(g, __shfl_xor(g, 1, 64));       // group max over 8 adjacent lanes
            g = max(g, __shfl_xor(g, 2, 64));
            g = max(g, __shfl_xor(g, 4, 64));
            int sh = 0;
            while (g > (255 << sh)) ++sh;           // == clip(ceil(log2(max(g,1)/255)),0,)
            float rqf = fminf(rintf(val * (1.0f / (float)(1 << sh))), 255.0f);
            sc[row][j * 64 + lane] = ((int)rqf) << sh;   // r = r_q << r_shift (exact int)
        }
    }

    // ===================== RV: out = r @ vt^T (exact int32) =====================
    // thread tile: rows {4*wave..4*wave+3}, chans {lane, lane+64}
    int acc[4][2];
    #pragma unroll
    for (int i = 0; i < 4; ++i) { acc[i][0] = 0; acc[i][1] = 0; }
    for (int sb = 0; sb < S_N / SB; ++sb) {
        __syncthreads();
        {   // stage vt block: kv[ch*VST + s], dequantized
            const int s_off = tid & 63;
            const int s0 = sb * SB;
            for (int ch = tid >> 6; ch < HC_N; ch += 4) {
                int m   = vt_q[(size_t)(bh * HC_N + ch) * S_N + s0 + s_off];
                int sft = vt_s[(bh * HC_N + ch) * (S_N / 8) + ((s0 + s_off) >> 3)];
                kv[ch * VST + s_off] = m << sft;
            }
        }
        __syncthreads();
        const int base = sb * SB;
        const int r0 = wave * 4;
        #pragma unroll 2
        for (int ss = 0; ss < SB; ss += 4) {
            v4i v0 = *(const v4i*)&kv[lane * VST + ss];
            v4i v1 = *(const v4i*)&kv[(lane + 64) * VST + ss];
            #pragma unroll
            for (int i = 0; i < 4; ++i) {
                v4i rv = *(const v4i*)&sc[r0 + i][base + ss];   // broadcast read
                #pragma unroll
                for (int j = 0; j < 4; ++j) {
                    acc[i][0] += __mul24(rv[j], v0[j]);   // r<=32640, |vt|<=1024: fits i24
                    acc[i][1] += __mul24(rv[j], v1[j]);
                }
            }
        }
    }
    #pragma unroll
    for (int i = 0; i < 4; ++i) {
        const int row = wave * 4 + i;
        size_t o = (size_t)(bh * T_N + t0 + row) * HC_N;
        out[o + lane]      = acc[i][0];   // int32 raw — harness reads np.int32
        out[o + lane + 64] = acc[i][1];
    }
}

extern "C" void kernel_launch(void* const* d_in, const int* in_sizes, int n_in,
                              void* d_out, int out_size, void* d_ws, size_t ws_size,
                              hipStream_t stream) {
    const int* q_q  = (const int*)d_in[0];
    const int* q_s  = (const int*)d_in[1];
    const int* k_q  = (const int*)d_in[2];
    const int* k_s  = (const int*)d_in[3];
    const int* vt_q = (const int*)d_in[4];
    const int* vt_s = (const int*)d_in[5];
    int* out = (int*)d_out;

    dim3 grid(T_N / TT, BH_N);
    mha_int_kernel<<<grid, dim3(256), 0, stream>>>(q_q, q_s, k_q, k_s, vt_q, vt_s, out);
}

// Round 3
// 243.510 us; speedup vs baseline: 5.3668x; 5.3668x over previous
//
#include <hip/hip_runtime.h>

// Integer-quantized MHA via i8 MFMA digit decomposition. Exact int32 semantics.
// B=2,H=16 (BH=32), T=S=1024, HC=128, G=8. Output int32.

typedef int v4i __attribute__((ext_vector_type(4)));
typedef long long i64;

#define BHN 32
#define TN  1024
#define SN  1024
#define HCN 128
#define TT  16
#define WS_NEED (3u*8388608u)

__device__ __forceinline__ unsigned pack_b(int b0,int b1,int b2,int b3){
    return (unsigned)((b0&255)|((b1&255)<<8)|((b2&255)<<16)|((b3&255)<<24));
}

// ---------------- pre-pass: digitize q/k/vt into packed i8 digit arrays ----------------
// qd: [bh*1024+t][2][128]                       (linear)
// kd: [bh*8+chunk][2][row128][granule-swizzled 128B]   (chunk image = LDS image)
// vd: same as kd with row=channel, cols=s-local
__global__ __launch_bounds__(256) void digitize(
    const int* __restrict__ q_q, const int* __restrict__ q_s,
    const int* __restrict__ k_q, const int* __restrict__ k_s,
    const int* __restrict__ vt_q, const int* __restrict__ vt_s,
    unsigned char* __restrict__ qd, unsigned char* __restrict__ kd,
    unsigned char* __restrict__ vd)
{
    const int t = blockIdx.x*256 + threadIdx.x;
    const int which = blockIdx.y;
    if (which <= 1){
        const int* src = which ? k_q : q_q;
        const int* ss  = which ? k_s : q_s;
        int idx = t*4;
        int row = idx >> 7, c0 = idx & 127;
        v4i m = *(const v4i*)(src + idx);
        int s = ss[(row<<4) + (c0>>3)];
        int d0=m[0]<<s, d1=m[1]<<s, d2=m[2]<<s, d3=m[3]<<s;
        unsigned hw = pack_b(d0>>4,d1>>4,d2>>4,d3>>4);
        unsigned lw = pack_b(d0&15,d1&15,d2&15,d3&15);
        if (which == 0){
            *(unsigned*)(qd + row*256 + c0)       = hw;
            *(unsigned*)(qd + row*256 + 128 + c0) = lw;
        } else {
            int bh = row>>10, sg = row & 1023;
            int ch = sg>>7, lr = sg & 127;
            unsigned base = (unsigned)(bh*8 + ch)*32768u + (unsigned)lr*128u;
            unsigned g8 = (unsigned)(((((c0>>3) ^ (lr&15)))<<3) | (c0&4));
            *(unsigned*)(kd + base + g8)         = hw;
            *(unsigned*)(kd + base + 16384 + g8) = lw;
        }
    } else {
        int idx = t*4;
        int row = idx >> 10, s0 = idx & 1023;   // row = bh*128+chan
        v4i m = *(const v4i*)(vt_q + idx);
        int s = vt_s[(row<<7) + (s0>>3)];
        int d0=m[0]<<s, d1=m[1]<<s, d2=m[2]<<s, d3=m[3]<<s;
        unsigned hw = pack_b(d0>>4,d1>>4,d2>>4,d3>>4);
        unsigned lw = pack_b(d0&15,d1&15,d2&15,d3&15);
        int bh = row>>7, chan = row & 127;
        int ch = s0>>7, sl = s0 & 127;
        unsigned base = (unsigned)(bh*8 + ch)*32768u + (unsigned)chan*128u;
        unsigned g8 = (unsigned)(((((sl>>3) ^ (chan&15)))<<3) | (sl&4));
        *(unsigned*)(vd + base + g8)         = hw;
        *(unsigned*)(vd + base + 16384 + g8) = lw;
    }
}

// ---------------- main fused kernel ----------------
template<bool PK>
__global__ __launch_bounds__(256,2) void mha_mfma(
    const int* __restrict__ q_q, const int* __restrict__ q_s,
    const int* __restrict__ k_q, const int* __restrict__ k_s,
    const int* __restrict__ vt_q, const int* __restrict__ vt_s,
    const unsigned char* __restrict__ qd, const unsigned char* __restrict__ kd,
    const unsigned char* __restrict__ vd, int* __restrict__ out)
{
    __shared__ unsigned char  kdig[2*128*128];   // 32 KB staging (K digits / VT digits)
    __shared__ unsigned short rbuf[16*1024];     // 32 KB r values u16, 8B-granule swizzle

    const int tid = threadIdx.x;
    const int ln  = tid & 15;
    const int qd4 = (tid >> 4) & 3;   // quad within wave
    const int w   = tid >> 6;
    const int bh  = blockIdx.y;
    const int t0  = blockIdx.x * TT;

    // ---- Q A-fragments (held in registers for whole phase 1) ----
    i64 qfh[4], qfl[4];
    if (PK){
        const unsigned char* qrow = qd + (size_t)(bh*TN + t0 + ln)*256;
        #pragma unroll
        for (int k=0;k<4;k++){
            int off = k*32 + qd4*8;
            qfh[k] = *(const i64*)(qrow + off);
            qfl[k] = *(const i64*)(qrow + 128 + off);
        }
    } else {
        const int* qrow = q_q + (size_t)(bh*TN + t0 + ln)*128;
        const int* srow = q_s + (size_t)(bh*TN + t0 + ln)*16;
        #pragma unroll
        for (int k=0;k<4;k++){
            int off = k*32 + qd4*8;
            v4i m0 = *(const v4i*)(qrow + off);
            v4i m1 = *(const v4i*)(qrow + off + 4);
            int s = srow[k*4 + qd4];
            int d0=m0[0]<<s,d1=m0[1]<<s,d2=m0[2]<<s,d3=m0[3]<<s;
            int e0=m1[0]<<s,e1=m1[1]<<s,e2=m1[2]<<s,e3=m1[3]<<s;
            qfh[k] = (i64)pack_b(d0>>4,d1>>4,d2>>4,d3>>4)
                   | ((i64)pack_b(e0>>4,e1>>4,e2>>4,e3>>4) << 32);
            qfl[k] = (i64)pack_b(d0&15,d1&15,d2&15,d3&15)
                   | ((i64)pack_b(e0&15,e1&15,e2&15,e3&15) << 32);
        }
    }

    int scv[16][4];   // scores / exp values, MFMA C-layout, 16 S-tiles x 4 rows

    // ================= phase 1: QK scores =================
    for (int ch=0; ch<8; ++ch){
        __syncthreads();
        if (PK){
            const unsigned char* src = kd + (size_t)(bh*8 + ch)*32768;
            #pragma unroll
            for (int i=0;i<8;i++){
                int off = tid*16 + i*4096;
                *(v4i*)(kdig + off) = *(const v4i*)(src + off);
            }
        } else {
            #pragma unroll
            for (int i=0;i<16;i++){
                int row = (tid>>5) + i*8;
                int c0  = (tid&31)*4;
                const int* kr = k_q + (size_t)(bh*SN + ch*128 + row)*128 + c0;
                v4i m = *(const v4i*)kr;
                int s = k_s[(size_t)(bh*SN + ch*128 + row)*16 + (c0>>3)];
                int d0=m[0]<<s,d1=m[1]<<s,d2=m[2]<<s,d3=m[3]<<s;
                unsigned g8 = (unsigned)((((c0>>3)^(row&15))<<3) | (c0&4));
                *(unsigned*)(kdig + row*128 + g8)         = pack_b(d0>>4,d1>>4,d2>>4,d3>>4);
                *(unsigned*)(kdig + 16384 + row*128 + g8) = pack_b(d0&15,d1&15,d2&15,d3&15);
            }
        }
        __syncthreads();
        #pragma unroll
        for (int i=0;i<2;i++){
            int n0 = (w*2+i)*16;
            int rowb = (n0+ln)*128;
            v4i a2{0,0,0,0}, a1{0,0,0,0}, a0{0,0,0,0};
            #pragma unroll
            for (int k=0;k<4;k++){
                int swz = (((k*4+qd4) ^ ln) << 3);
                i64 bh_ = *(const i64*)(kdig + rowb + swz);
                i64 bl_ = *(const i64*)(kdig + 16384 + rowb + swz);
                a2 = __builtin_amdgcn_mfma_i32_16x16x32_i8(qfh[k], bh_, a2, 0,0,0);
                a1 = __builtin_amdgcn_mfma_i32_16x16x32_i8(qfl[k], bh_, a1, 0,0,0);
                a1 = __builtin_amdgcn_mfma_i32_16x16x32_i8(qfh[k], bl_, a1, 0,0,0);
                a0 = __builtin_amdgcn_mfma_i32_16x16x32_i8(qfl[k], bl_, a0, 0,0,0);
            }
            int st = ch*2 + i;
            #pragma unroll
            for (int r=0;r<4;r++)
                scv[st][r] = (a2[r]<<8) + (a1[r]<<4) + a0[r];
        }
    }

    // ================= softmax + group-of-8 po2 requant =================
    __syncthreads();                       // kdig -> red reuse
    float* red = (float*)kdig;             // [2][4 waves][16 rows]
    const float CS = (float)(6.103515625e-05 / 11.313708498984760390566); // f32(2^-14/sqrt(128))
    float mx[4], sm[4];
    #pragma unroll
    for (int r=0;r<4;r++){
        float m_ = -3.0e38f;
        #pragma unroll
        for (int st=0;st<16;st++) m_ = fmaxf(m_, (float)scv[st][r]*CS);
        #pragma unroll
        for (int o=8;o>0;o>>=1) m_ = fmaxf(m_, __shfl_xor(m_, o));
        mx[r] = m_;
    }
    if (ln == 0){
        #pragma unroll
        for (int r=0;r<4;r++) red[w*16 + qd4*4 + r] = mx[r];
    }
    __syncthreads();
    #pragma unroll
    for (int r=0;r<4;r++){
        float m_ = red[qd4*4+r];
        m_ = fmaxf(m_, red[16 + qd4*4+r]);
        m_ = fmaxf(m_, red[32 + qd4*4+r]);
        m_ = fmaxf(m_, red[48 + qd4*4+r]);
        mx[r] = m_;
        float s_ = 0.f;
        #pragma unroll
        for (int st=0;st<16;st++){
            float e = expf((float)scv[st][r]*CS - m_);
            scv[st][r] = __float_as_int(e);
            s_ += e;
        }
        #pragma unroll
        for (int o=8;o>0;o>>=1) s_ += __shfl_xor(s_, o);
        sm[r] = s_;
    }
    if (ln == 0){
        #pragma unroll
        for (int r=0;r<4;r++) red[64 + w*16 + qd4*4 + r] = sm[r];
    }
    __syncthreads();
    #pragma unroll
    for (int r=0;r<4;r++)
        sm[r] = red[64+qd4*4+r] + red[80+qd4*4+r] + red[96+qd4*4+r] + red[112+qd4*4+r];

    #pragma unroll
    for (int st=0;st<16;st++){
        int colb = (st>>1)*128 + (w*2+(st&1))*16;
        #pragma unroll
        for (int r=0;r<4;r++){
            float p   = __int_as_float(scv[st][r]) / sm[r];   // IEEE div, matches ref
            float val = rintf(p * 16384.0f);
            float g = val;
            g = fmaxf(g, __shfl_xor(g, 1));
            g = fmaxf(g, __shfl_xor(g, 2));
            g = fmaxf(g, __shfl_xor(g, 4));
            int gi = (int)g;
            int sh = (gi>255)+(gi>510)+(gi>1020)+(gi>2040)+(gi>4080)+(gi>8160)+(gi>16320);
            float rq = fminf(rintf(val * __int_as_float((127-sh)<<23)), 255.0f);
            int rv = ((int)rq) << sh;                         // r <= 16384
            int row = qd4*4 + r;
            int col = colb + ln;
            int gsw = (col>>2) ^ (row<<1);                    // 8B-granule swizzle
            rbuf[row*1024 + gsw*4 + (col&3)] = (unsigned short)rv;
        }
    }

    // ================= phase 2: out = r @ vt^T =================
    v4i acc[2][4];
    #pragma unroll
    for (int i=0;i<2;i++){
        #pragma unroll
        for (int j=0;j<4;j++) acc[i][j] = v4i{0,0,0,0};
    }
    for (int ch=0; ch<8; ++ch){
        __syncthreads();
        if (PK){
            const unsigned char* src = vd + (size_t)(bh*8 + ch)*32768;
            #pragma unroll
            for (int i=0;i<8;i++){
                int off = tid*16 + i*4096;
                *(v4i*)(kdig + off) = *(const v4i*)(src + off);
            }
        } else {
            #pragma unroll
            for (int i=0;i<16;i++){
                int row = (tid>>5) + i*8;          // channel
                int s4  = (tid&31)*4;              // s within chunk
                const int* vr = vt_q + (size_t)(bh*HCN + row)*SN + ch*128 + s4;
                v4i m = *(const v4i*)vr;
                int s = vt_s[(size_t)(bh*HCN + row)*128 + ch*16 + (s4>>3)];
                int d0=m[0]<<s,d1=m[1]<<s,d2=m[2]<<s,d3=m[3]<<s;
                unsigned g8 = (unsigned)((((s4>>3)^(row&15))<<3) | (s4&4));
                *(unsigned*)(kdig + row*128 + g8)         = pack_b(d0>>4,d1>>4,d2>>4,d3>>4);
                *(unsigned*)(kdig + 16384 + row*128 + g8) = pack_b(d0&15,d1&15,d2&15,d3&15);
            }
        }
        __syncthreads();
        #pragma unroll
        for (int k=0;k<4;k++){
            int base = ch*128 + k*32 + qd4*8;               // u16 index into r row
            int g0 = (base>>2) ^ (ln<<1);
            const unsigned short* rp = rbuf + ln*1024 + g0*4;
            i64 u01 = *(const i64*)(rp);
            i64 u23 = *(const i64*)(rp+4);
            unsigned u0=(unsigned)u01, u1=(unsigned)(u01>>32);
            unsigned u2=(unsigned)u23, u3=(unsigned)(u23>>32);
            unsigned t0_=u0+0x00800080u, t1_=u1+0x00800080u,
                     t2_=u2+0x00800080u, t3_=u3+0x00800080u;
            i64 rh = (i64)(unsigned)__builtin_amdgcn_perm(t1_, t0_, 0x07050301u)
                   | ((i64)(unsigned)__builtin_amdgcn_perm(t3_, t2_, 0x07050301u) << 32);
            i64 rl = (i64)(unsigned)__builtin_amdgcn_perm(u1, u0, 0x06040200u)
                   | ((i64)(unsigned)__builtin_amdgcn_perm(u3, u2, 0x06040200u) << 32);
            #pragma unroll
            for (int i=0;i<2;i++){
                int c0 = (w*2+i)*16;
                int rowb = (c0+ln)*128;
                int swz = (((k*4+qd4) ^ ln) << 3);
                i64 vh = *(const i64*)(kdig + rowb + swz);
                i64 vl = *(const i64*)(kdig + 16384 + rowb + swz);
                acc[i][0] = __builtin_amdgcn_mfma_i32_16x16x32_i8(rh, vh, acc[i][0], 0,0,0);
                acc[i][1] = __builtin_amdgcn_mfma_i32_16x16x32_i8(rh, vl, acc[i][1], 0,0,0);
                acc[i][2] = __builtin_amdgcn_mfma_i32_16x16x32_i8(rl, vh, acc[i][2], 0,0,0);
                acc[i][3] = __builtin_amdgcn_mfma_i32_16x16x32_i8(rl, vl, acc[i][3], 0,0,0);
            }
        }
    }
    // epilogue: out = 4096*HH + 256*HL + 16*LH + LL  (r = rh*256+rl, v = vh*16+vl)
    #pragma unroll
    for (int i=0;i<2;i++){
        #pragma unroll
        for (int r=0;r<4;r++){
            int o = (acc[i][0][r]<<12) + (acc[i][1][r]<<8) + (acc[i][2][r]<<4) + acc[i][3][r];
            out[(size_t)(bh*TN + t0 + qd4*4 + r)*HCN + (w*2+i)*16 + ln] = o;
        }
    }
}

extern "C" void kernel_launch(void* const* d_in, const int* in_sizes, int n_in,
                              void* d_out, int out_size, void* d_ws, size_t ws_size,
                              hipStream_t stream) {
    const int* q_q  = (const int*)d_in[0];
    const int* q_s  = (const int*)d_in[1];
    const int* k_q  = (const int*)d_in[2];
    const int* k_s  = (const int*)d_in[3];
    const int* vt_q = (const int*)d_in[4];
    const int* vt_s = (const int*)d_in[5];
    int* out = (int*)d_out;

    unsigned char* qd = (unsigned char*)d_ws;
    unsigned char* kd = qd + 8388608;
    unsigned char* vd = qd + 16777216;

    if (ws_size >= (size_t)WS_NEED){
        digitize<<<dim3(4096,3), 256, 0, stream>>>(q_q,q_s,k_q,k_s,vt_q,vt_s, qd,kd,vd);
        mha_mfma<true><<<dim3(TN/TT, BHN), 256, 0, stream>>>(
            q_q,q_s,k_q,k_s,vt_q,vt_s, qd,kd,vd, out);
    } else {
        mha_mfma<false><<<dim3(TN/TT, BHN), 256, 0, stream>>>(
            q_q,q_s,k_q,k_s,vt_q,vt_s, qd,kd,vd, out);
    }
}

// Round 4
// 214.720 us; speedup vs baseline: 6.0864x; 1.1341x over previous
//
#include <hip/hip_runtime.h>

// Integer-quantized MHA via i8 K=64 MFMA digit decomposition. Exact int32 GEMMs.
// B=2,H=16 (BH=32), T=S=1024, HC=128, G=8. Output int32.

typedef int v4i __attribute__((ext_vector_type(4)));

#define BHN 32
#define TN  1024
#define SN  1024
#define HCN 128
#define TT  16
#define WS_NEED (2u*8388608u)

__device__ __forceinline__ unsigned pack_b(int b0,int b1,int b2,int b3){
    return (unsigned)((b0&255)|((b1&255)<<8)|((b2&255)<<16)|((b3&255)<<24));
}

// digitize 16 consecutive dequantized ints (2 scale groups) into hi/lo i8 digit vectors
__device__ __forceinline__ void dig16(const int* __restrict__ p, int s0, int s1,
                                      v4i& hi, v4i& lo){
    #pragma unroll
    for (int wi=0; wi<4; ++wi){
        v4i m = *(const v4i*)(p + wi*4);
        int s = (wi<2) ? s0 : s1;
        int d0=m[0]<<s, d1=m[1]<<s, d2=m[2]<<s, d3=m[3]<<s;
        hi[wi] = (int)pack_b(d0>>4,d1>>4,d2>>4,d3>>4);
        lo[wi] = (int)pack_b(d0&15,d1&15,d2&15,d3&15);
    }
}

// ---------------- pre-pass: digitize K and VT into linear chunk images ----------------
// kd/vd: [bh*8+chunk][plane(2)][row(128)][128 bytes linear]  (32768 B per chunk)
__global__ __launch_bounds__(256) void digitize(
    const int* __restrict__ k_q, const int* __restrict__ k_s,
    const int* __restrict__ vt_q, const int* __restrict__ vt_s,
    unsigned char* __restrict__ kd, unsigned char* __restrict__ vd)
{
    const int g = blockIdx.x*256 + threadIdx.x;
    const int ioff = g*16;
    if (blockIdx.y == 0){
        int row = ioff>>7, c0 = ioff&127;              // row over 32*1024
        int s0 = k_s[(row<<4)+(c0>>3)], s1 = k_s[(row<<4)+(c0>>3)+1];
        v4i hi, lo;
        dig16(k_q + ioff, s0, s1, hi, lo);
        int bh = row>>10, ch = (row>>7)&7, lr = row&127;
        size_t base = (size_t)(bh*8+ch)*32768u + (size_t)lr*128u + (size_t)c0;
        *(v4i*)(kd + base)         = hi;
        *(v4i*)(kd + base + 16384) = lo;
    } else {
        int grow = ioff>>10, s4 = ioff&1023;           // grow = bh*128+chan
        int s0 = vt_s[(grow<<7)+(s4>>3)], s1 = vt_s[(grow<<7)+(s4>>3)+1];
        v4i hi, lo;
        dig16(vt_q + ioff, s0, s1, hi, lo);
        int bh = grow>>7, chan = grow&127, ch = s4>>7, sl = s4&127;
        size_t base = (size_t)(bh*8+ch)*32768u + (size_t)chan*128u + (size_t)sl;
        *(v4i*)(vd + base)         = hi;
        *(v4i*)(vd + base + 16384) = lo;
    }
}

// ---------------- main fused kernel ----------------
template<bool PK>
__global__ __launch_bounds__(256,2) void mha_mfma(
    const int* __restrict__ q_q, const int* __restrict__ q_s,
    const int* __restrict__ k_q, const int* __restrict__ k_s,
    const int* __restrict__ vt_q, const int* __restrict__ vt_s,
    const unsigned char* __restrict__ kd, const unsigned char* __restrict__ vd,
    int* __restrict__ out)
{
    __shared__ unsigned char  kdig[2*128*128];   // 32 KB staging (16B-granule XOR swizzle)
    __shared__ unsigned short rbuf[16*1024];     // 32 KB r values u16, granule swizzle

    const int tid = threadIdx.x;
    const int ln  = tid & 15;
    const int qd4 = (tid >> 4) & 3;
    const int w   = tid >> 6;
    const int bh  = blockIdx.y;
    const int t0  = blockIdx.x * TT;

    // ---- Q A-fragments in registers (digitized in-reg from global) ----
    v4i qfh[2], qfl[2];
    {
        const int* qrow  = q_q + (size_t)(bh*TN + t0 + ln)*HCN;
        const int* qsrow = q_s + (size_t)(bh*TN + t0 + ln)*16;
        #pragma unroll
        for (int kc=0; kc<2; ++kc){
            int gi = kc*8 + qd4*2;
            dig16(qrow + kc*64 + qd4*16, qsrow[gi], qsrow[gi+1], qfh[kc], qfl[kc]);
        }
    }

    int scv[16][4];   // scores / exp bits, MFMA C-layout: row=qd4*4+r, col=tile*16+ln

    // ================= phase 1: QK scores =================
    for (int ch=0; ch<8; ++ch){
        __syncthreads();
        if (PK){
            const unsigned char* src = kd + (size_t)(bh*8 + ch)*32768u;
            #pragma unroll
            for (int i=0;i<8;i++){
                int off = tid*16 + i*4096;
                int row = (off>>7)&127, g16 = (off>>4)&7;
                int ldo = (off & ~127) | ((g16 ^ (row&7))<<4);
                *(v4i*)(kdig + ldo) = *(const v4i*)(src + off);
            }
        } else {
            #pragma unroll
            for (int i=0;i<4;i++){
                int off = tid*16 + i*4096;             // int index within 128x128 chunk
                int row = off>>7, c0 = off&127;
                int gb = (size_t)0, gidx = ((bh*SN + ch*128 + row)<<4) + (c0>>3);
                (void)gb;
                v4i hi, lo;
                dig16(k_q + (size_t)(bh*SN + ch*128 + row)*128 + c0,
                      k_s[gidx], k_s[gidx+1], hi, lo);
                int sw = ((c0>>4) ^ (row&7))<<4;
                *(v4i*)(kdig + row*128 + sw)         = hi;
                *(v4i*)(kdig + 16384 + row*128 + sw) = lo;
            }
        }
        __syncthreads();
        #pragma unroll
        for (int i=0;i<2;i++){
            int rowb = ((w*2+i)*16 + ln)*128;
            v4i a2{0,0,0,0}, a1{0,0,0,0}, a0{0,0,0,0};
            #pragma unroll
            for (int kc=0;kc<2;kc++){
                int sw = ((kc*4+qd4) ^ (ln&7))<<4;
                v4i bhv = *(const v4i*)(kdig + rowb + sw);
                v4i blv = *(const v4i*)(kdig + 16384 + rowb + sw);
                a2 = __builtin_amdgcn_mfma_i32_16x16x64_i8(qfh[kc], bhv, a2, 0,0,0);
                a1 = __builtin_amdgcn_mfma_i32_16x16x64_i8(qfl[kc], bhv, a1, 0,0,0);
                a1 = __builtin_amdgcn_mfma_i32_16x16x64_i8(qfh[kc], blv, a1, 0,0,0);
                a0 = __builtin_amdgcn_mfma_i32_16x16x64_i8(qfl[kc], blv, a0, 0,0,0);
            }
            int st = ch*2 + i;
            #pragma unroll
            for (int r=0;r<4;r++)
                scv[st][r] = (a2[r]<<8) + (a1[r]<<4) + a0[r];
        }
    }

    // ================= softmax + group-of-8 po2 requant =================
    __syncthreads();
    float* red = (float*)kdig;      // reuse staging LDS for cross-wave reduction
    const float CS = (float)(6.103515625e-05 / 11.313708498984760390566); // f32(2^-14/sqrt(128))
    float mx[4], sm[4];
    #pragma unroll
    for (int r=0;r<4;r++){
        float m_ = -3.0e38f;
        #pragma unroll
        for (int st=0;st<16;st++) m_ = fmaxf(m_, (float)scv[st][r]*CS);
        #pragma unroll
        for (int o=8;o>0;o>>=1) m_ = fmaxf(m_, __shfl_xor(m_, o));
        mx[r] = m_;
    }
    if (ln == 0){
        #pragma unroll
        for (int r=0;r<4;r++) red[w*16 + qd4*4 + r] = mx[r];
    }
    __syncthreads();
    #pragma unroll
    for (int r=0;r<4;r++){
        float m_ = fmaxf(fmaxf(red[qd4*4+r], red[16+qd4*4+r]),
                         fmaxf(red[32+qd4*4+r], red[48+qd4*4+r]));
        float s_ = 0.f;
        #pragma unroll
        for (int st=0;st<16;st++){
            float e = expf((float)scv[st][r]*CS - m_);
            scv[st][r] = __float_as_int(e);
            s_ += e;
        }
        #pragma unroll
        for (int o=8;o>0;o>>=1) s_ += __shfl_xor(s_, o);
        sm[r] = s_;
    }
    if (ln == 0){
        #pragma unroll
        for (int r=0;r<4;r++) red[64 + w*16 + qd4*4 + r] = sm[r];
    }
    __syncthreads();
    float inv14[4];
    #pragma unroll
    for (int r=0;r<4;r++){
        float s_ = red[64+qd4*4+r] + red[80+qd4*4+r] + red[96+qd4*4+r] + red[112+qd4*4+r];
        inv14[r] = 16384.0f / s_;      // one IEEE div per row (was 64 per lane)
    }

    #pragma unroll
    for (int st=0;st<16;st++){
        int colb = (st>>1)*128 + (w*2+(st&1))*16;
        #pragma unroll
        for (int r=0;r<4;r++){
            float val = rintf(__int_as_float(scv[st][r]) * inv14[r]);
            float g = val;
            g = fmaxf(g, __shfl_xor(g, 1));
            g = fmaxf(g, __shfl_xor(g, 2));
            g = fmaxf(g, __shfl_xor(g, 4));
            int gi = max((int)g, 1);
            int x = gi - 1;
            int e = 31 - __clz(x | 255);
            int sh = (e - 7) + ((x >> (e - 7)) == 255);   // == clip(ceil(log2(gi/255)),0,)
            float rq = fminf(rintf(val * __int_as_float((127-sh)<<23)), 255.0f);
            int rv = ((int)rq) << sh;                     // r <= 16384
            int row = qd4*4 + r;
            int col = colb + ln;
            int gs  = (col>>3) ^ (row&7);
            rbuf[row*1024 + gs*8 + (col&7)] = (unsigned short)rv;
        }
    }

    // ================= phase 2: out = r @ vt^T =================
    v4i acc[2][4];
    #pragma unroll
    for (int i=0;i<2;i++){
        #pragma unroll
        for (int j=0;j<4;j++) acc[i][j] = v4i{0,0,0,0};
    }
    for (int ch=0; ch<8; ++ch){
        __syncthreads();
        if (PK){
            const unsigned char* src = vd + (size_t)(bh*8 + ch)*32768u;
            #pragma unroll
            for (int i=0;i<8;i++){
                int off = tid*16 + i*4096;
                int row = (off>>7)&127, g16 = (off>>4)&7;
                int ldo = (off & ~127) | ((g16 ^ (row&7))<<4);
                *(v4i*)(kdig + ldo) = *(const v4i*)(src + off);
            }
        } else {
            #pragma unroll
            for (int i=0;i<4;i++){
                int off = tid*16 + i*4096;
                int chan = off>>7, s4 = off&127;
                int gidx = ((bh*HCN + chan)<<7) + ch*16 + (s4>>3);
                v4i hi, lo;
                dig16(vt_q + (size_t)(bh*HCN + chan)*SN + ch*128 + s4,
                      vt_s[gidx], vt_s[gidx+1], hi, lo);
                int sw = ((s4>>4) ^ (chan&7))<<4;
                *(v4i*)(kdig + chan*128 + sw)         = hi;
                *(v4i*)(kdig + 16384 + chan*128 + sw) = lo;
            }
        }
        __syncthreads();
        #pragma unroll
        for (int kc=0;kc<2;kc++){
            int cb = ch*128 + kc*64 + qd4*16;
            int gg = cb>>3;
            const unsigned short* rp = rbuf + ln*1024;
            v4i r01 = *(const v4i*)(rp + ((gg    ^ (ln&7))<<3));
            v4i r23 = *(const v4i*)(rp + (((gg+1)^ (ln&7))<<3));
            unsigned u0=(unsigned)r01[0], u1=(unsigned)r01[1],
                     u2=(unsigned)r01[2], u3=(unsigned)r01[3],
                     u4=(unsigned)r23[0], u5=(unsigned)r23[1],
                     u6=(unsigned)r23[2], u7=(unsigned)r23[3];
            v4i rlv, rhv;
            rlv[0] = (int)__builtin_amdgcn_perm(u1, u0, 0x06040200u);
            rlv[1] = (int)__builtin_amdgcn_perm(u3, u2, 0x06040200u);
            rlv[2] = (int)__builtin_amdgcn_perm(u5, u4, 0x06040200u);
            rlv[3] = (int)__builtin_amdgcn_perm(u7, u6, 0x06040200u);
            rhv[0] = (int)__builtin_amdgcn_perm(u1+0x00800080u, u0+0x00800080u, 0x07050301u);
            rhv[1] = (int)__builtin_amdgcn_perm(u3+0x00800080u, u2+0x00800080u, 0x07050301u);
            rhv[2] = (int)__builtin_amdgcn_perm(u5+0x00800080u, u4+0x00800080u, 0x07050301u);
            rhv[3] = (int)__builtin_amdgcn_perm(u7+0x00800080u, u6+0x00800080u, 0x07050301u);
            #pragma unroll
            for (int i=0;i<2;i++){
                int rowb = ((w*2+i)*16 + ln)*128;
                int sw = ((kc*4+qd4) ^ (ln&7))<<4;
                v4i vh = *(const v4i*)(kdig + rowb + sw);
                v4i vl = *(const v4i*)(kdig + 16384 + rowb + sw);
                acc[i][0] = __builtin_amdgcn_mfma_i32_16x16x64_i8(rhv, vh, acc[i][0], 0,0,0);
                acc[i][1] = __builtin_amdgcn_mfma_i32_16x16x64_i8(rhv, vl, acc[i][1], 0,0,0);
                acc[i][2] = __builtin_amdgcn_mfma_i32_16x16x64_i8(rlv, vh, acc[i][2], 0,0,0);
                acc[i][3] = __builtin_amdgcn_mfma_i32_16x16x64_i8(rlv, vl, acc[i][3], 0,0,0);
            }
        }
    }
    // epilogue: out = 4096*HH + 256*HL + 16*LH + LL  (r = rh*256+rl, v = vh*16+vl)
    #pragma unroll
    for (int i=0;i<2;i++){
        #pragma unroll
        for (int r=0;r<4;r++){
            int o = (acc[i][0][r]<<12) + (acc[i][1][r]<<8) + (acc[i][2][r]<<4) + acc[i][3][r];
            out[(size_t)(bh*TN + t0 + qd4*4 + r)*HCN + (w*2+i)*16 + ln] = o;
        }
    }
}

extern "C" void kernel_launch(void* const* d_in, const int* in_sizes, int n_in,
                              void* d_out, int out_size, void* d_ws, size_t ws_size,
                              hipStream_t stream) {
    const int* q_q  = (const int*)d_in[0];
    const int* q_s  = (const int*)d_in[1];
    const int* k_q  = (const int*)d_in[2];
    const int* k_s  = (const int*)d_in[3];
    const int* vt_q = (const int*)d_in[4];
    const int* vt_s = (const int*)d_in[5];
    int* out = (int*)d_out;

    unsigned char* kd = (unsigned char*)d_ws;
    unsigned char* vd = kd + 8388608;

    if (ws_size >= (size_t)WS_NEED){
        digitize<<<dim3(1024,2), 256, 0, stream>>>(k_q,k_s,vt_q,vt_s, kd,vd);
        mha_mfma<true><<<dim3(TN/TT, BHN), 256, 0, stream>>>(
            q_q,q_s,k_q,k_s,vt_q,vt_s, kd,vd, out);
    } else {
        mha_mfma<false><<<dim3(TN/TT, BHN), 256, 0, stream>>>(
            q_q,q_s,k_q,k_s,vt_q,vt_s, kd,vd, out);
    }
}

// Round 5
// 210.065 us; speedup vs baseline: 6.2213x; 1.0222x over previous
//
#include <hip/hip_runtime.h>

// Integer-quantized MHA via i8 K=64 MFMA digit decomposition. Exact int32 GEMMs.
// B=2,H=16 (BH=32), T=S=1024, HC=128, G=8. Output int32.
// R5: XCD-aware block swizzle + pre-swizzled digit images + global_load_lds staging
//     + padded rbuf stride (bank-conflict-free). No numeric changes vs R4.

typedef int v4i __attribute__((ext_vector_type(4)));

#define BHN 32
#define TN  1024
#define SN  1024
#define HCN 128
#define TT  16
#define RST 1032              // rbuf row stride in u16: 2064 B == 16 mod 128 -> conflict-free
#define WS_NEED (2u*8388608u)

__device__ __forceinline__ unsigned pack_b(int b0,int b1,int b2,int b3){
    return (unsigned)((b0&255)|((b1&255)<<8)|((b2&255)<<16)|((b3&255)<<24));
}

__device__ __forceinline__ void g2l16(const void* g, void* l){
    __builtin_amdgcn_global_load_lds((const __attribute__((address_space(1))) void*)g,
                                     (__attribute__((address_space(3))) void*)l, 16, 0, 0);
}

// digitize 16 consecutive dequantized ints (2 scale groups) into hi/lo i8 digit vectors
__device__ __forceinline__ void dig16(const int* __restrict__ p, int s0, int s1,
                                      v4i& hi, v4i& lo){
    #pragma unroll
    for (int wi=0; wi<4; ++wi){
        v4i m = *(const v4i*)(p + wi*4);
        int s = (wi<2) ? s0 : s1;
        int d0=m[0]<<s, d1=m[1]<<s, d2=m[2]<<s, d3=m[3]<<s;
        hi[wi] = (int)pack_b(d0>>4,d1>>4,d2>>4,d3>>4);
        lo[wi] = (int)pack_b(d0&15,d1&15,d2&15,d3&15);
    }
}

// ---------------- pre-pass: digitize K and VT into PRE-SWIZZLED chunk images ----------------
// kd/vd: [bh*8+chunk][plane(2)][row(128)][8 granules of 16B, granule g at g^(row&7)]
__global__ __launch_bounds__(256) void digitize(
    const int* __restrict__ k_q, const int* __restrict__ k_s,
    const int* __restrict__ vt_q, const int* __restrict__ vt_s,
    unsigned char* __restrict__ kd, unsigned char* __restrict__ vd)
{
    const int g = blockIdx.x*256 + threadIdx.x;
    const int ioff = g*16;
    if (blockIdx.y == 0){
        int row = ioff>>7, c0 = ioff&127;              // row over 32*1024
        int s0 = k_s[(row<<4)+(c0>>3)], s1 = k_s[(row<<4)+(c0>>3)+1];
        v4i hi, lo;
        dig16(k_q + ioff, s0, s1, hi, lo);
        int bh = row>>10, ch = (row>>7)&7, lr = row&127;
        int sw = (((c0>>4) ^ (lr&7))<<4);
        size_t base = (size_t)(bh*8+ch)*32768u + (size_t)lr*128u + (size_t)sw;
        *(v4i*)(kd + base)         = hi;
        *(v4i*)(kd + base + 16384) = lo;
    } else {
        int grow = ioff>>10, s4 = ioff&1023;           // grow = bh*128+chan
        int s0 = vt_s[(grow<<7)+(s4>>3)], s1 = vt_s[(grow<<7)+(s4>>3)+1];
        v4i hi, lo;
        dig16(vt_q + ioff, s0, s1, hi, lo);
        int bh = grow>>7, chan = grow&127, ch = s4>>7, sl = s4&127;
        int sw = (((sl>>4) ^ (chan&7))<<4);
        size_t base = (size_t)(bh*8+ch)*32768u + (size_t)chan*128u + (size_t)sw;
        *(v4i*)(vd + base)         = hi;
        *(v4i*)(vd + base + 16384) = lo;
    }
}

// ---------------- main fused kernel ----------------
template<bool PK>
__global__ __launch_bounds__(256,2) void mha_mfma(
    const int* __restrict__ q_q, const int* __restrict__ q_s,
    const int* __restrict__ k_q, const int* __restrict__ k_s,
    const int* __restrict__ vt_q, const int* __restrict__ vt_s,
    const unsigned char* __restrict__ kd, const unsigned char* __restrict__ vd,
    int* __restrict__ out)
{
    __shared__ unsigned char  kdig[2*128*128];   // 32 KB staging (16B-granule XOR swizzle)
    __shared__ unsigned short rbuf[16*RST];      // 33 KB r values u16, padded stride

    const int tid = threadIdx.x;
    const int ln  = tid & 15;
    const int qd4 = (tid >> 4) & 3;
    const int w   = tid >> 6;
    // XCD-aware swizzle: consecutive dispatch indices round-robin XCDs; make each
    // XCD's share cover only 4 bh so K/V digit images (2 MB) fit its 4 MB L2.
    const int blk = blockIdx.x;
    const int bh  = ((blk>>9)<<3) | (blk&7);
    const int t0  = ((blk>>3)&63) * TT;

    // ---- Q A-fragments in registers (digitized in-reg from global) ----
    v4i qfh[2], qfl[2];
    {
        const int* qrow  = q_q + (size_t)(bh*TN + t0 + ln)*HCN;
        const int* qsrow = q_s + (size_t)(bh*TN + t0 + ln)*16;
        #pragma unroll
        for (int kc=0; kc<2; ++kc){
            int gi = kc*8 + qd4*2;
            dig16(qrow + kc*64 + qd4*16, qsrow[gi], qsrow[gi+1], qfh[kc], qfl[kc]);
        }
    }

    int scv[16][4];   // scores / exp bits, MFMA C-layout: row=qd4*4+r, col=tile*16+ln

    // ================= phase 1: QK scores =================
    for (int ch=0; ch<8; ++ch){
        __syncthreads();
        if (PK){
            const unsigned char* gsrc = kd + (size_t)(bh*8 + ch)*32768u + w*1024 + (tid&63)*16;
            unsigned char* ldst = kdig + w*1024;   // wave-uniform base; HW adds lane*16
            #pragma unroll
            for (int i=0;i<8;i++)
                g2l16(gsrc + i*4096, ldst + i*4096);
        } else {
            #pragma unroll
            for (int i=0;i<4;i++){
                int off = tid*16 + i*4096;             // int index within 128x128 chunk
                int row = off>>7, c0 = off&127;
                int gidx = ((bh*SN + ch*128 + row)<<4) + (c0>>3);
                v4i hi, lo;
                dig16(k_q + (size_t)(bh*SN + ch*128 + row)*128 + c0,
                      k_s[gidx], k_s[gidx+1], hi, lo);
                int sw = ((c0>>4) ^ (row&7))<<4;
                *(v4i*)(kdig + row*128 + sw)         = hi;
                *(v4i*)(kdig + 16384 + row*128 + sw) = lo;
            }
        }
        __syncthreads();
        #pragma unroll
        for (int i=0;i<2;i++){
            int rowb = ((w*2+i)*16 + ln)*128;
            v4i a2{0,0,0,0}, a1{0,0,0,0}, a0{0,0,0,0};
            #pragma unroll
            for (int kc=0;kc<2;kc++){
                int sw = ((kc*4+qd4) ^ (ln&7))<<4;
                v4i bhv = *(const v4i*)(kdig + rowb + sw);
                v4i blv = *(const v4i*)(kdig + 16384 + rowb + sw);
                a2 = __builtin_amdgcn_mfma_i32_16x16x64_i8(qfh[kc], bhv, a2, 0,0,0);
                a1 = __builtin_amdgcn_mfma_i32_16x16x64_i8(qfl[kc], bhv, a1, 0,0,0);
                a1 = __builtin_amdgcn_mfma_i32_16x16x64_i8(qfh[kc], blv, a1, 0,0,0);
                a0 = __builtin_amdgcn_mfma_i32_16x16x64_i8(qfl[kc], blv, a0, 0,0,0);
            }
            int st = ch*2 + i;
            #pragma unroll
            for (int r=0;r<4;r++)
                scv[st][r] = (a2[r]<<8) + (a1[r]<<4) + a0[r];
        }
    }

    // ================= softmax + group-of-8 po2 requant =================
    __syncthreads();
    float* red = (float*)kdig;      // reuse staging LDS for cross-wave reduction
    const float CS = (float)(6.103515625e-05 / 11.313708498984760390566); // f32(2^-14/sqrt(128))
    float mx[4], sm[4];
    #pragma unroll
    for (int r=0;r<4;r++){
        float m_ = -3.0e38f;
        #pragma unroll
        for (int st=0;st<16;st++) m_ = fmaxf(m_, (float)scv[st][r]*CS);
        #pragma unroll
        for (int o=8;o>0;o>>=1) m_ = fmaxf(m_, __shfl_xor(m_, o));
        mx[r] = m_;
    }
    if (ln == 0){
        #pragma unroll
        for (int r=0;r<4;r++) red[w*16 + qd4*4 + r] = mx[r];
    }
    __syncthreads();
    #pragma unroll
    for (int r=0;r<4;r++){
        float m_ = fmaxf(fmaxf(red[qd4*4+r], red[16+qd4*4+r]),
                         fmaxf(red[32+qd4*4+r], red[48+qd4*4+r]));
        float s_ = 0.f;
        #pragma unroll
        for (int st=0;st<16;st++){
            float e = expf((float)scv[st][r]*CS - m_);
            scv[st][r] = __float_as_int(e);
            s_ += e;
        }
        #pragma unroll
        for (int o=8;o>0;o>>=1) s_ += __shfl_xor(s_, o);
        sm[r] = s_;
    }
    if (ln == 0){
        #pragma unroll
        for (int r=0;r<4;r++) red[64 + w*16 + qd4*4 + r] = sm[r];
    }
    __syncthreads();
    float inv14[4];
    #pragma unroll
    for (int r=0;r<4;r++){
        float s_ = red[64+qd4*4+r] + red[80+qd4*4+r] + red[96+qd4*4+r] + red[112+qd4*4+r];
        inv14[r] = 16384.0f / s_;      // one IEEE div per row
    }

    #pragma unroll
    for (int st=0;st<16;st++){
        int colb = (st>>1)*128 + (w*2+(st&1))*16;
        #pragma unroll
        for (int r=0;r<4;r++){
            float val = rintf(__int_as_float(scv[st][r]) * inv14[r]);
            float g = val;
            g = fmaxf(g, __shfl_xor(g, 1));
            g = fmaxf(g, __shfl_xor(g, 2));
            g = fmaxf(g, __shfl_xor(g, 4));
            int gi = max((int)g, 1);
            int x = gi - 1;
            int e = 31 - __clz(x | 255);
            int sh = (e - 7) + ((x >> (e - 7)) == 255);   // == clip(ceil(log2(gi/255)),0,)
            float rq = fminf(rintf(val * __int_as_float((127-sh)<<23)), 255.0f);
            int rv = ((int)rq) << sh;                     // r <= 16384
            int row = qd4*4 + r;
            int col = colb + ln;
            int gs  = (col>>3) ^ (row&7);
            rbuf[row*RST + gs*8 + (col&7)] = (unsigned short)rv;
        }
    }

    // ================= phase 2: out = r @ vt^T =================
    v4i acc[2][4];
    #pragma unroll
    for (int i=0;i<2;i++){
        #pragma unroll
        for (int j=0;j<4;j++) acc[i][j] = v4i{0,0,0,0};
    }
    for (int ch=0; ch<8; ++ch){
        __syncthreads();
        if (PK){
            const unsigned char* gsrc = vd + (size_t)(bh*8 + ch)*32768u + w*1024 + (tid&63)*16;
            unsigned char* ldst = kdig + w*1024;
            #pragma unroll
            for (int i=0;i<8;i++)
                g2l16(gsrc + i*4096, ldst + i*4096);
        } else {
            #pragma unroll
            for (int i=0;i<4;i++){
                int off = tid*16 + i*4096;
                int chan = off>>7, s4 = off&127;
                int gidx = ((bh*HCN + chan)<<7) + ch*16 + (s4>>3);
                v4i hi, lo;
                dig16(vt_q + (size_t)(bh*HCN + chan)*SN + ch*128 + s4,
                      vt_s[gidx], vt_s[gidx+1], hi, lo);
                int sw = ((s4>>4) ^ (chan&7))<<4;
                *(v4i*)(kdig + chan*128 + sw)         = hi;
                *(v4i*)(kdig + 16384 + chan*128 + sw) = lo;
            }
        }
        __syncthreads();
        #pragma unroll
        for (int kc=0;kc<2;kc++){
            int cb = ch*128 + kc*64 + qd4*16;
            int gg = cb>>3;
            const unsigned short* rp = rbuf + ln*RST;
            v4i r01 = *(const v4i*)(rp + ((gg    ^ (ln&7))<<3));
            v4i r23 = *(const v4i*)(rp + (((gg+1)^ (ln&7))<<3));
            unsigned u0=(unsigned)r01[0], u1=(unsigned)r01[1],
                     u2=(unsigned)r01[2], u3=(unsigned)r01[3],
                     u4=(unsigned)r23[0], u5=(unsigned)r23[1],
                     u6=(unsigned)r23[2], u7=(unsigned)r23[3];
            v4i rlv, rhv;
            rlv[0] = (int)__builtin_amdgcn_perm(u1, u0, 0x06040200u);
            rlv[1] = (int)__builtin_amdgcn_perm(u3, u2, 0x06040200u);
            rlv[2] = (int)__builtin_amdgcn_perm(u5, u4, 0x06040200u);
            rlv[3] = (int)__builtin_amdgcn_perm(u7, u6, 0x06040200u);
            rhv[0] = (int)__builtin_amdgcn_perm(u1+0x00800080u, u0+0x00800080u, 0x07050301u);
            rhv[1] = (int)__builtin_amdgcn_perm(u3+0x00800080u, u2+0x00800080u, 0x07050301u);
            rhv[2] = (int)__builtin_amdgcn_perm(u5+0x00800080u, u4+0x00800080u, 0x07050301u);
            rhv[3] = (int)__builtin_amdgcn_perm(u7+0x00800080u, u6+0x00800080u, 0x07050301u);
            #pragma unroll
            for (int i=0;i<2;i++){
                int rowb = ((w*2+i)*16 + ln)*128;
                int sw = ((kc*4+qd4) ^ (ln&7))<<4;
                v4i vh = *(const v4i*)(kdig + rowb + sw);
                v4i vl = *(const v4i*)(kdig + 16384 + rowb + sw);
                acc[i][0] = __builtin_amdgcn_mfma_i32_16x16x64_i8(rhv, vh, acc[i][0], 0,0,0);
                acc[i][1] = __builtin_amdgcn_mfma_i32_16x16x64_i8(rhv, vl, acc[i][1], 0,0,0);
                acc[i][2] = __builtin_amdgcn_mfma_i32_16x16x64_i8(rlv, vh, acc[i][2], 0,0,0);
                acc[i][3] = __builtin_amdgcn_mfma_i32_16x16x64_i8(rlv, vl, acc[i][3], 0,0,0);
            }
        }
    }
    // epilogue: out = 4096*HH + 256*HL + 16*LH + LL  (r = rh*256+rl, v = vh*16+vl)
    #pragma unroll
    for (int i=0;i<2;i++){
        #pragma unroll
        for (int r=0;r<4;r++){
            int o = (acc[i][0][r]<<12) + (acc[i][1][r]<<8) + (acc[i][2][r]<<4) + acc[i][3][r];
            out[(size_t)(bh*TN + t0 + qd4*4 + r)*HCN + (w*2+i)*16 + ln] = o;
        }
    }
}

extern "C" void kernel_launch(void* const* d_in, const int* in_sizes, int n_in,
                              void* d_out, int out_size, void* d_ws, size_t ws_size,
                              hipStream_t stream) {
    const int* q_q  = (const int*)d_in[0];
    const int* q_s  = (const int*)d_in[1];
    const int* k_q  = (const int*)d_in[2];
    const int* k_s  = (const int*)d_in[3];
    const int* vt_q = (const int*)d_in[4];
    const int* vt_s = (const int*)d_in[5];
    int* out = (int*)d_out;

    unsigned char* kd = (unsigned char*)d_ws;
    unsigned char* vd = kd + 8388608;

    if (ws_size >= (size_t)WS_NEED){
        digitize<<<dim3(1024,2), 256, 0, stream>>>(k_q,k_s,vt_q,vt_s, kd,vd);
        mha_mfma<true><<<dim3(2048), 256, 0, stream>>>(
            q_q,q_s,k_q,k_s,vt_q,vt_s, kd,vd, out);
    } else {
        mha_mfma<false><<<dim3(2048), 256, 0, stream>>>(
            q_q,q_s,k_q,k_s,vt_q,vt_s, kd,vd, out);
    }
}

// Round 6
// 174.083 us; speedup vs baseline: 7.5071x; 1.2067x over previous
//
#include <hip/hip_runtime.h>

// Integer-quantized MHA via i8 K=64 MFMA digit decomposition. Exact int32 GEMMs.
// B=2,H=16 (BH=32), T=S=1024, HC=128, G=8. Output int32.
// R6: barrier-free GEMM loops. B-operands read directly from global in MFMA
//     fragment order (pre-packed by digitize); LDS holds only r + reductions
//     -> 33.5 KB -> 4 blocks/CU. No numeric changes vs R5 (absmax must stay 65536).

typedef int v4i __attribute__((ext_vector_type(4)));

#define BHN 32
#define TN  1024
#define SN  1024
#define HCN 128
#define TT  16
#define RST 1032              // rbuf row stride in u16: 2064 B == 16 mod 128 -> conflict-free
#define WS_NEED (2u*8388608u)

__device__ __forceinline__ unsigned pack_b(int b0,int b1,int b2,int b3){
    return (unsigned)((b0&255)|((b1&255)<<8)|((b2&255)<<16)|((b3&255)<<24));
}

// digitize 16 consecutive dequantized ints (2 scale groups) into hi/lo i8 digit vectors
__device__ __forceinline__ void dig16(const int* __restrict__ p, int s0, int s1,
                                      v4i& hi, v4i& lo){
    #pragma unroll
    for (int wi=0; wi<4; ++wi){
        v4i m = *(const v4i*)(p + wi*4);
        int s = (wi<2) ? s0 : s1;
        int d0=m[0]<<s, d1=m[1]<<s, d2=m[2]<<s, d3=m[3]<<s;
        hi[wi] = (int)pack_b(d0>>4,d1>>4,d2>>4,d3>>4);
        lo[wi] = (int)pack_b(d0&15,d1&15,d2&15,d3&15);
    }
}

// ---------------- pre-pass: digitize K and VT into FRAGMENT-ORDERED chunk images ----
// kd/vd: [bh*8+ch] 32KB chunk = [tile n(8)][kc(2)][plane(2)][lane(64)][16B]
// so a wave's MFMA B-operand (plane) is one contiguous 1 KB slab, lane*16 each.
__global__ __launch_bounds__(256) void digitize(
    const int* __restrict__ k_q, const int* __restrict__ k_s,
    const int* __restrict__ vt_q, const int* __restrict__ vt_s,
    unsigned char* __restrict__ kd, unsigned char* __restrict__ vd)
{
    const int g = blockIdx.x*256 + threadIdx.x;
    const int ioff = g*16;
    if (blockIdx.y == 0){
        int row = ioff>>7, c0 = ioff&127;              // row over 32*1024 s-rows
        int s0 = k_s[(row<<4)+(c0>>3)], s1 = k_s[(row<<4)+(c0>>3)+1];
        v4i hi, lo;
        dig16(k_q + ioff, s0, s1, hi, lo);
        int bh = row>>10, srow = row&1023;
        int ch = srow>>7, lr = srow&127, n = lr>>4, ln = lr&15;
        int kc = c0>>6, q4 = (c0>>4)&3;
        size_t base = (size_t)(bh*8+ch)*32768u
                    + (size_t)(n*4096 + kc*2048 + (q4*16+ln)*16);
        *(v4i*)(kd + base)        = hi;
        *(v4i*)(kd + base + 1024) = lo;
    } else {
        int grow = ioff>>10, s4 = ioff&1023;           // grow = bh*128+chan
        int s0 = vt_s[(grow<<7)+(s4>>3)], s1 = vt_s[(grow<<7)+(s4>>3)+1];
        v4i hi, lo;
        dig16(vt_q + ioff, s0, s1, hi, lo);
        int bh = grow>>7, chan = grow&127;
        int ch = s4>>7, sl = s4&127;
        int n = chan>>4, ln = chan&15;
        int kc = sl>>6, q4 = (sl>>4)&3;
        size_t base = (size_t)(bh*8+ch)*32768u
                    + (size_t)(n*4096 + kc*2048 + (q4*16+ln)*16);
        *(v4i*)(vd + base)        = hi;
        *(v4i*)(vd + base + 1024) = lo;
    }
}

// ---------------- main fused kernel ----------------
template<bool PK>
__global__ __launch_bounds__(256,4) void mha_mfma(
    const int* __restrict__ q_q, const int* __restrict__ q_s,
    const int* __restrict__ k_q, const int* __restrict__ k_s,
    const int* __restrict__ vt_q, const int* __restrict__ vt_s,
    const unsigned char* __restrict__ kd, const unsigned char* __restrict__ vd,
    int* __restrict__ out)
{
    __shared__ unsigned short rbuf[16*RST];      // 33 KB r values u16, padded stride
    __shared__ float red[128];                   // cross-wave softmax reductions

    const int tid  = threadIdx.x;
    const int ln   = tid & 15;
    const int qd4  = (tid >> 4) & 3;
    const int w    = tid >> 6;
    const int lane = tid & 63;
    // XCD-aware swizzle: each XCD's share covers only 4 bh -> 2 MB digit images in its L2.
    const int blk = blockIdx.x;
    const int bh  = ((blk>>9)<<3) | (blk&7);
    const int t0  = ((blk>>3)&63) * TT;

    // ---- Q A-fragments in registers (digitized in-reg from global) ----
    v4i qfh[2], qfl[2];
    {
        const int* qrow  = q_q + (size_t)(bh*TN + t0 + ln)*HCN;
        const int* qsrow = q_s + (size_t)(bh*TN + t0 + ln)*16;
        #pragma unroll
        for (int kc=0; kc<2; ++kc){
            int gi = kc*8 + qd4*2;
            dig16(qrow + kc*64 + qd4*16, qsrow[gi], qsrow[gi+1], qfh[kc], qfl[kc]);
        }
    }

    int scv[16][4];   // scores / exp bits, MFMA C-layout: row=qd4*4+r, col=tile*16+ln

    // ================= phase 1: QK scores (barrier-free) =================
    const v4i* kb = (const v4i*)(kd + (size_t)bh*262144u);
    for (int ch=0; ch<8; ++ch){
        #pragma unroll
        for (int i=0;i<2;i++){
            const int n = w*2 + i;
            v4i a2{0,0,0,0}, a1{0,0,0,0}, a0{0,0,0,0};
            #pragma unroll
            for (int kc=0;kc<2;kc++){
                v4i bhv, blv;
                if (PK){
                    const v4i* tb = kb + (ch*8+n)*256 + kc*128 + lane;
                    bhv = tb[0];
                    blv = tb[64];
                } else {
                    int srow = bh*SN + ch*128 + n*16 + ln;
                    int cc   = kc*64 + qd4*16;
                    dig16(k_q + (size_t)srow*128 + cc,
                          k_s[srow*16 + (cc>>3)], k_s[srow*16 + (cc>>3) + 1], bhv, blv);
                }
                a2 = __builtin_amdgcn_mfma_i32_16x16x64_i8(qfh[kc], bhv, a2, 0,0,0);
                a1 = __builtin_amdgcn_mfma_i32_16x16x64_i8(qfl[kc], bhv, a1, 0,0,0);
                a1 = __builtin_amdgcn_mfma_i32_16x16x64_i8(qfh[kc], blv, a1, 0,0,0);
                a0 = __builtin_amdgcn_mfma_i32_16x16x64_i8(qfl[kc], blv, a0, 0,0,0);
            }
            int st = ch*2 + i;
            #pragma unroll
            for (int r=0;r<4;r++)
                scv[st][r] = (a2[r]<<8) + (a1[r]<<4) + a0[r];
        }
    }

    // ================= softmax + group-of-8 po2 requant =================
    const float CS = (float)(6.103515625e-05 / 11.313708498984760390566); // f32(2^-14/sqrt(128))
    float mx[4], sm[4];
    #pragma unroll
    for (int r=0;r<4;r++){
        float m_ = -3.0e38f;
        #pragma unroll
        for (int st=0;st<16;st++) m_ = fmaxf(m_, (float)scv[st][r]*CS);
        #pragma unroll
        for (int o=8;o>0;o>>=1) m_ = fmaxf(m_, __shfl_xor(m_, o));
        mx[r] = m_;
    }
    if (ln == 0){
        #pragma unroll
        for (int r=0;r<4;r++) red[w*16 + qd4*4 + r] = mx[r];
    }
    __syncthreads();
    #pragma unroll
    for (int r=0;r<4;r++){
        float m_ = fmaxf(fmaxf(red[qd4*4+r], red[16+qd4*4+r]),
                         fmaxf(red[32+qd4*4+r], red[48+qd4*4+r]));
        float s_ = 0.f;
        #pragma unroll
        for (int st=0;st<16;st++){
            float e = expf((float)scv[st][r]*CS - m_);
            scv[st][r] = __float_as_int(e);
            s_ += e;
        }
        #pragma unroll
        for (int o=8;o>0;o>>=1) s_ += __shfl_xor(s_, o);
        sm[r] = s_;
    }
    if (ln == 0){
        #pragma unroll
        for (int r=0;r<4;r++) red[64 + w*16 + qd4*4 + r] = sm[r];
    }
    __syncthreads();
    float inv14[4];
    #pragma unroll
    for (int r=0;r<4;r++){
        float s_ = red[64+qd4*4+r] + red[80+qd4*4+r] + red[96+qd4*4+r] + red[112+qd4*4+r];
        inv14[r] = 16384.0f / s_;      // one IEEE div per row
    }

    #pragma unroll
    for (int st=0;st<16;st++){
        int colb = (st>>1)*128 + (w*2+(st&1))*16;
        #pragma unroll
        for (int r=0;r<4;r++){
            float val = rintf(__int_as_float(scv[st][r]) * inv14[r]);
            float g = val;
            g = fmaxf(g, __shfl_xor(g, 1));
            g = fmaxf(g, __shfl_xor(g, 2));
            g = fmaxf(g, __shfl_xor(g, 4));
            int gi = max((int)g, 1);
            int x = gi - 1;
            int e = 31 - __clz(x | 255);
            int sh = (e - 7) + ((x >> (e - 7)) == 255);   // == clip(ceil(log2(gi/255)),0,)
            float rq = fminf(rintf(val * __int_as_float((127-sh)<<23)), 255.0f);
            int rv = ((int)rq) << sh;                     // r <= 16384
            int row = qd4*4 + r;
            int col = colb + ln;
            int gs  = (col>>3) ^ (row&7);
            rbuf[row*RST + gs*8 + (col&7)] = (unsigned short)rv;
        }
    }
    __syncthreads();

    // ================= phase 2: out = r @ vt^T (barrier-free) =================
    const v4i* vb = (const v4i*)(vd + (size_t)bh*262144u);
    v4i acc[2][4];
    #pragma unroll
    for (int i=0;i<2;i++){
        #pragma unroll
        for (int j=0;j<4;j++) acc[i][j] = v4i{0,0,0,0};
    }
    for (int ch=0; ch<8; ++ch){
        #pragma unroll
        for (int kc=0;kc<2;kc++){
            // A-fragments: digit-split r from LDS
            int cb = ch*128 + kc*64 + qd4*16;
            int gg = cb>>3;
            const unsigned short* rp = rbuf + ln*RST;
            v4i r01 = *(const v4i*)(rp + ((gg    ^ (ln&7))<<3));
            v4i r23 = *(const v4i*)(rp + (((gg+1)^ (ln&7))<<3));
            unsigned u0=(unsigned)r01[0], u1=(unsigned)r01[1],
                     u2=(unsigned)r01[2], u3=(unsigned)r01[3],
                     u4=(unsigned)r23[0], u5=(unsigned)r23[1],
                     u6=(unsigned)r23[2], u7=(unsigned)r23[3];
            v4i rlv, rhv;
            rlv[0] = (int)__builtin_amdgcn_perm(u1, u0, 0x06040200u);
            rlv[1] = (int)__builtin_amdgcn_perm(u3, u2, 0x06040200u);
            rlv[2] = (int)__builtin_amdgcn_perm(u5, u4, 0x06040200u);
            rlv[3] = (int)__builtin_amdgcn_perm(u7, u6, 0x06040200u);
            rhv[0] = (int)__builtin_amdgcn_perm(u1+0x00800080u, u0+0x00800080u, 0x07050301u);
            rhv[1] = (int)__builtin_amdgcn_perm(u3+0x00800080u, u2+0x00800080u, 0x07050301u);
            rhv[2] = (int)__builtin_amdgcn_perm(u5+0x00800080u, u4+0x00800080u, 0x07050301u);
            rhv[3] = (int)__builtin_amdgcn_perm(u7+0x00800080u, u6+0x00800080u, 0x07050301u);
            #pragma unroll
            for (int i=0;i<2;i++){
                const int n = w*2 + i;
                v4i vh, vl;
                if (PK){
                    const v4i* tb = vb + (ch*8+n)*256 + kc*128 + lane;
                    vh = tb[0];
                    vl = tb[64];
                } else {
                    int chan = n*16 + ln;
                    int ss   = ch*128 + kc*64 + qd4*16;
                    dig16(vt_q + (size_t)(bh*HCN + chan)*SN + ss,
                          vt_s[(bh*HCN + chan)*128 + (ss>>3)],
                          vt_s[(bh*HCN + chan)*128 + (ss>>3) + 1], vh, vl);
                }
                acc[i][0] = __builtin_amdgcn_mfma_i32_16x16x64_i8(rhv, vh, acc[i][0], 0,0,0);
                acc[i][1] = __builtin_amdgcn_mfma_i32_16x16x64_i8(rhv, vl, acc[i][1], 0,0,0);
                acc[i][2] = __builtin_amdgcn_mfma_i32_16x16x64_i8(rlv, vh, acc[i][2], 0,0,0);
                acc[i][3] = __builtin_amdgcn_mfma_i32_16x16x64_i8(rlv, vl, acc[i][3], 0,0,0);
            }
        }
    }
    // epilogue: out = 4096*HH + 256*HL + 16*LH + LL  (r = rh*256+rl, v = vh*16+vl)
    #pragma unroll
    for (int i=0;i<2;i++){
        #pragma unroll
        for (int r=0;r<4;r++){
            int o = (acc[i][0][r]<<12) + (acc[i][1][r]<<8) + (acc[i][2][r]<<4) + acc[i][3][r];
            out[(size_t)(bh*TN + t0 + qd4*4 + r)*HCN + (w*2+i)*16 + ln] = o;
        }
    }
}

extern "C" void kernel_launch(void* const* d_in, const int* in_sizes, int n_in,
                              void* d_out, int out_size, void* d_ws, size_t ws_size,
                              hipStream_t stream) {
    const int* q_q  = (const int*)d_in[0];
    const int* q_s  = (const int*)d_in[1];
    const int* k_q  = (const int*)d_in[2];
    const int* k_s  = (const int*)d_in[3];
    const int* vt_q = (const int*)d_in[4];
    const int* vt_s = (const int*)d_in[5];
    int* out = (int*)d_out;

    unsigned char* kd = (unsigned char*)d_ws;
    unsigned char* vd = kd + 8388608;

    if (ws_size >= (size_t)WS_NEED){
        digitize<<<dim3(1024,2), 256, 0, stream>>>(k_q,k_s,vt_q,vt_s, kd,vd);
        mha_mfma<true><<<dim3(2048), 256, 0, stream>>>(
            q_q,q_s,k_q,k_s,vt_q,vt_s, kd,vd, out);
    } else {
        mha_mfma<false><<<dim3(2048), 256, 0, stream>>>(
            q_q,q_s,k_q,k_s,vt_q,vt_s, kd,vd, out);
    }
}